// Round 1
// baseline (788.470 us; speedup 1.0000x reference)
//
#include <hip/hip_runtime.h>

// ---------------------------------------------------------------------------
// EncoderLayer: pre-LN attn (gated by iter!=0) + causal-mult-mask attention +
// residual + pre-LN FFN(GELU) + residual.  B=8 S=1024 D=1024 FF=4096 H=16 Dh=64
// Round 0 baseline: bf16 MFMA GEMMs (m97-style 128^2 tile, global_load_lds 16B),
// attention materialized in 4 chunks of 32 heads (scores buffer aliases h2).
// Workspace budget ~166 MB.
// ---------------------------------------------------------------------------

#define B_N 8
#define SEQ 1024
#define DM 1024
#define DFF 4096
#define NH 16
#define DH 64
#define MROWS (B_N * SEQ) // 8192

typedef __attribute__((ext_vector_type(4))) float f32x4;
typedef __attribute__((ext_vector_type(8))) short short8;
typedef __attribute__((ext_vector_type(4))) unsigned short us4;
typedef unsigned short u16;

__device__ __forceinline__ float b2f(u16 u) { return __uint_as_float(((unsigned)u) << 16); }
__device__ __forceinline__ u16 f2b(float f) {
    unsigned u = __float_as_uint(f);
    return (u16)((u + 0x7fffu + ((u >> 16) & 1u)) >> 16); // RNE
}
__device__ __forceinline__ float gelu_f(float x) {
    float t = tanhf(0.7978845608028654f * (x + 0.044715f * x * x * x));
    return 0.5f * x * (1.0f + t);
}
__device__ __forceinline__ void async_cp16(const void* g, void* l) {
    __builtin_amdgcn_global_load_lds(
        (const __attribute__((address_space(1))) unsigned int*)g,
        (__attribute__((address_space(3))) unsigned int*)l, 16, 0, 0);
}

// ---------------------------------------------------------------------------
// Generic bf16 MFMA GEMM:  C[m][n] = sum_k A[m][k] * Bt[n][k]   (Bt = B^T)
// Batched over blockIdx.z with per-operand base = (z/16)*s1 + (z%16)*s2 (elems).
// Block: 256 thr = 4 waves; wave tile 64x64 (4x4 mfma_f32_16x16x32_bf16).
//   WC=2 -> waves 2x2 (tile 128x128);  WC=1 -> waves 4x1 (tile 256x64).
// EPI: 0 = bf16 out, v=(acc+bias)*scale; 1 = + GELU; 2 = fp32 C += v (residual)
// ---------------------------------------------------------------------------
template <int TM, int TN, int WC, int EPI>
__global__ __launch_bounds__(256) void gemm_bf16(
    const u16* __restrict__ A, long long sA1, long long sA2, int lda,
    const u16* __restrict__ Bt, long long sB1, long long sB2, int ldb,
    void* __restrict__ C, long long sC1, long long sC2, int ldc,
    const float* __restrict__ bias, float scale, int K)
{
    __shared__ __align__(16) u16 smem[(TM + TN) * 32];
    u16* As = smem;
    u16* Bs = smem + TM * 32;

    const int tid = threadIdx.x;
    const int lane = tid & 63;
    const int w = tid >> 6;
    const int wr = w / WC, wc = w % WC;

    const int z = blockIdx.z;
    const int zq = z >> 4, zr = z & 15;
    const u16* Ab = A + (long long)zq * sA1 + (long long)zr * sA2;
    const u16* Bb = Bt + (long long)zq * sB1 + (long long)zr * sB2;

    const int m0 = blockIdx.y * TM;
    const int n0 = blockIdx.x * TN;

    f32x4 acc[4][4];
#pragma unroll
    for (int i = 0; i < 4; i++)
#pragma unroll
        for (int j = 0; j < 4; j++)
#pragma unroll
            for (int e = 0; e < 4; e++) acc[i][j][e] = 0.f;

    for (int kt = 0; kt < K; kt += 32) {
        // stage A tile [TM][32] bf16 (row-major, 64B rows) via global_load_lds
#pragma unroll
        for (int i = 0; i < TM / 64; i++) {
            int g = tid + i * 256;
            int row = g >> 2;
            int cole = (g & 3) << 3; // element col (8 bf16 per 16B granule)
            async_cp16(Ab + (size_t)(m0 + row) * lda + kt + cole, (char*)As + g * 16);
        }
#pragma unroll
        for (int i = 0; i < TN / 64; i++) {
            int g = tid + i * 256;
            int row = g >> 2;
            int cole = (g & 3) << 3;
            async_cp16(Bb + (size_t)(n0 + row) * ldb + kt + cole, (char*)Bs + g * 16);
        }
        __syncthreads(); // drains vmcnt for the async loads

        short8 af[4], bfr[4];
        const int rr = lane & 15;
        const int kb = (lane >> 4) << 3;
#pragma unroll
        for (int mi = 0; mi < 4; mi++)
            af[mi] = *(const short8*)&As[(wr * 64 + mi * 16 + rr) * 32 + kb];
#pragma unroll
        for (int ni = 0; ni < 4; ni++)
            bfr[ni] = *(const short8*)&Bs[(wc * 64 + ni * 16 + rr) * 32 + kb];
#pragma unroll
        for (int mi = 0; mi < 4; mi++)
#pragma unroll
            for (int ni = 0; ni < 4; ni++)
                acc[mi][ni] = __builtin_amdgcn_mfma_f32_16x16x32_bf16(
                    af[mi], bfr[ni], acc[mi][ni], 0, 0, 0);
        __syncthreads();
    }

    // epilogue: C/D layout col=lane&15, row=(lane>>4)*4+j  [measured m89/m91]
    const long long cz = (long long)zq * sC1 + (long long)zr * sC2;
    const int r0 = (lane >> 4) << 2;
    const int ccol = lane & 15;
#pragma unroll
    for (int mi = 0; mi < 4; mi++) {
#pragma unroll
        for (int ni = 0; ni < 4; ni++) {
            int colg = n0 + wc * 64 + ni * 16 + ccol;
            float bv = bias ? bias[colg] : 0.f;
#pragma unroll
            for (int j = 0; j < 4; j++) {
                int rowg = m0 + wr * 64 + mi * 16 + r0 + j;
                float v = (acc[mi][ni][j] + bv) * scale;
                long long idx = cz + (long long)rowg * ldc + colg;
                if (EPI == 1) v = gelu_f(v);
                if (EPI == 2) {
                    float* Cf = (float*)C;
                    Cf[idx] += v;
                } else {
                    ((u16*)C)[idx] = f2b(v);
                }
            }
        }
    }
}

// ---------------------------------------------------------------------------
// LayerNorm over D=1024 -> bf16.  One block (256 thr) per row, float4 loads.
// iterp != null && *iterp==0  ->  passthrough (first-iteration gate).
// ---------------------------------------------------------------------------
__global__ __launch_bounds__(256) void ln_bf16(
    const float* __restrict__ in, const float* __restrict__ gg,
    const float* __restrict__ bb, u16* __restrict__ outp,
    const int* __restrict__ iterp)
{
    const int row = blockIdx.x;
    const int t = threadIdx.x;
    const int lane = t & 63, w = t >> 6;
    const float* r = in + (size_t)row * DM;
    f32x4 x = *(const f32x4*)(r + t * 4);
    __shared__ float red[4];

    float s = x[0] + x[1] + x[2] + x[3];
#pragma unroll
    for (int o = 32; o; o >>= 1) s += __shfl_xor(s, o, 64);
    if (lane == 0) red[w] = s;
    __syncthreads();
    float mu = (red[0] + red[1] + red[2] + red[3]) * (1.0f / DM);
    __syncthreads();

    float d0 = x[0] - mu, d1 = x[1] - mu, d2 = x[2] - mu, d3 = x[3] - mu;
    float q = d0 * d0 + d1 * d1 + d2 * d2 + d3 * d3;
#pragma unroll
    for (int o = 32; o; o >>= 1) q += __shfl_xor(q, o, 64);
    if (lane == 0) red[w] = q;
    __syncthreads();
    float rs = rsqrtf((red[0] + red[1] + red[2] + red[3]) * (1.0f / DM) + 1e-6f);

    bool apply = !(iterp && iterp[0] == 0);
    f32x4 gv = *(const f32x4*)(gg + t * 4);
    f32x4 bv = *(const f32x4*)(bb + t * 4);
    us4 o;
    if (apply) {
        o[0] = f2b(d0 * rs * gv[0] + bv[0]);
        o[1] = f2b(d1 * rs * gv[1] + bv[1]);
        o[2] = f2b(d2 * rs * gv[2] + bv[2]);
        o[3] = f2b(d3 * rs * gv[3] + bv[3]);
    } else {
        o[0] = f2b(x[0]); o[1] = f2b(x[1]); o[2] = f2b(x[2]); o[3] = f2b(x[3]);
    }
    *(us4*)(outp + (size_t)row * DM + t * 4) = o;
}

// ---------------------------------------------------------------------------
// Softmax with the reference's multiplicative tril mask: masked (k>q) entries
// become EXACTLY 0 and still participate in softmax (weight e^-m / Z).
// In-place on bf16 scores [32 heads][1024 q][1024 k]; block per (q, head).
// ---------------------------------------------------------------------------
__global__ __launch_bounds__(256) void softmax_mask(u16* __restrict__ sc)
{
    const int qrow = blockIdx.x;
    u16* rowp = sc + ((size_t)blockIdx.y << 20) + (size_t)qrow * SEQ;
    const int t = threadIdx.x, lane = t & 63, w = t >> 6;
    __shared__ float red[4];

    us4 r4 = *(const us4*)(rowp + t * 4);
    float v[4];
#pragma unroll
    for (int j = 0; j < 4; j++) {
        int k = t * 4 + j;
        v[j] = (k <= qrow) ? b2f(r4[j]) : 0.f;
    }
    float m = fmaxf(fmaxf(v[0], v[1]), fmaxf(v[2], v[3]));
#pragma unroll
    for (int o = 32; o; o >>= 1) m = fmaxf(m, __shfl_xor(m, o, 64));
    if (lane == 0) red[w] = m;
    __syncthreads();
    m = fmaxf(fmaxf(red[0], red[1]), fmaxf(red[2], red[3]));
    __syncthreads();
    float e0 = expf(v[0] - m), e1 = expf(v[1] - m), e2 = expf(v[2] - m), e3 = expf(v[3] - m);
    float s = e0 + e1 + e2 + e3;
#pragma unroll
    for (int o = 32; o; o >>= 1) s += __shfl_xor(s, o, 64);
    if (lane == 0) red[w] = s;
    __syncthreads();
    float inv = 1.0f / (red[0] + red[1] + red[2] + red[3]);
    us4 o;
    o[0] = f2b(e0 * inv); o[1] = f2b(e1 * inv); o[2] = f2b(e2 * inv); o[3] = f2b(e3 * inv);
    *(us4*)(rowp + t * 4) = o;
}

// W [Kd][Nd] fp32  ->  WT [Nd][Kd] bf16   (tiled transpose, block (32,8))
__global__ void transW(const float* __restrict__ W, u16* __restrict__ WT, int Kd, int Nd)
{
    __shared__ float tile[32][33];
    int bx = blockIdx.x << 5, by = blockIdx.y << 5;
    int tx = threadIdx.x, ty = threadIdx.y;
#pragma unroll
    for (int i = 0; i < 32; i += 8)
        tile[ty + i][tx] = W[(size_t)(by + ty + i) * Nd + bx + tx];
    __syncthreads();
#pragma unroll
    for (int i = 0; i < 32; i += 8)
        WT[(size_t)(bx + ty + i) * Kd + by + tx] = f2b(tile[tx][ty + i]);
}

// V flat [8192][1024] bf16 -> Vt [B*H][Dh][S] bf16 (per-head transpose)
__global__ void transV(const u16* __restrict__ Vb, u16* __restrict__ Vt)
{
    __shared__ u16 tile[32][33];
    int s0 = blockIdx.x << 5, d0 = blockIdx.y << 5, bh = blockIdx.z;
    int b = bh >> 4, h = bh & 15;
    int tx = threadIdx.x, ty = threadIdx.y;
#pragma unroll
    for (int i = 0; i < 32; i += 8)
        tile[ty + i][tx] = Vb[(size_t)((b << 10) + s0 + ty + i) * DM + (h << 6) + d0 + tx];
    __syncthreads();
#pragma unroll
    for (int i = 0; i < 32; i += 8)
        Vt[((size_t)bh << 16) + (size_t)(d0 + ty + i) * SEQ + s0 + tx] = tile[tx][ty + i];
}

// out = x + ctx (flat reinterpret of [B,H,S,Dh] as [B,S,H*Dh] -> linear add)
__global__ __launch_bounds__(256) void resid_add(
    const u16* __restrict__ ctx, const float* __restrict__ x, float* __restrict__ outp)
{
    size_t i = ((size_t)blockIdx.x * 256 + threadIdx.x) * 4;
    us4 c = *(const us4*)(ctx + i);
    f32x4 xv = *(const f32x4*)(x + i);
    f32x4 o;
#pragma unroll
    for (int j = 0; j < 4; j++) o[j] = xv[j] + b2f(c[j]);
    *(f32x4*)(outp + i) = o;
}

// ---------------------------------------------------------------------------
extern "C" void kernel_launch(void* const* d_in, const int* in_sizes, int n_in,
                              void* d_out, int out_size, void* d_ws, size_t ws_size,
                              hipStream_t stream)
{
    const int* iter = (const int*)d_in[0];
    const float* x = (const float*)d_in[1];
    /* d_in[2] = mask (unused; tril semantics hardcoded) */
    const float* Wq = (const float*)d_in[3];
    const float* bq = (const float*)d_in[4];
    const float* Wk = (const float*)d_in[5];
    const float* bk = (const float*)d_in[6];
    const float* Wv = (const float*)d_in[7];
    const float* bv = (const float*)d_in[8];
    const float* W1 = (const float*)d_in[9];
    const float* b1 = (const float*)d_in[10];
    const float* W2 = (const float*)d_in[11];
    const float* b2 = (const float*)d_in[12];
    const float* lag = (const float*)d_in[13];
    const float* lab = (const float*)d_in[14];
    const float* lfg = (const float*)d_in[15];
    const float* lfb = (const float*)d_in[16];
    float* out = (float*)d_out;

    char* ws = (char*)d_ws;
    size_t off = 0;
    auto alloc = [&](size_t bytes) {
        char* p = ws + off;
        off += (bytes + 255) & ~(size_t)255;
        return p;
    };
    u16* NXb = (u16*)alloc((size_t)MROWS * DM * 2); // 16MB; reused as Vt later
    u16* Qb  = (u16*)alloc((size_t)MROWS * DM * 2); // 16MB; reused as h1 later
    u16* Kb  = (u16*)alloc((size_t)MROWS * DM * 2); // 16MB
    u16* Vb  = (u16*)alloc((size_t)MROWS * DM * 2); // 16MB
    u16* ctx = (u16*)alloc((size_t)MROWS * DM * 2); // 16MB  [B][H][S][Dh]
    u16* h2  = (u16*)alloc((size_t)MROWS * DFF * 2); // 64MB; scores chunk earlier
    u16* WqT = (u16*)alloc((size_t)DM * DM * 2);
    u16* WkT = (u16*)alloc((size_t)DM * DM * 2);
    u16* WvT = (u16*)alloc((size_t)DM * DM * 2);
    u16* W1T = (u16*)alloc((size_t)DM * DFF * 2);
    u16* W2T = (u16*)alloc((size_t)DM * DFF * 2);
    u16* Vt = NXb;     // alias: NXb dead after projections
    u16* h1 = Qb;      // alias: Qb dead after attention
    u16* scores = h2;  // alias: h2 written only after attention

    dim3 tb(32, 8);
    // weights -> bf16 transposed [N][K]
    transW<<<dim3(DM / 32, DM / 32), tb, 0, stream>>>(Wq, WqT, DM, DM);
    transW<<<dim3(DM / 32, DM / 32), tb, 0, stream>>>(Wk, WkT, DM, DM);
    transW<<<dim3(DM / 32, DM / 32), tb, 0, stream>>>(Wv, WvT, DM, DM);
    transW<<<dim3(DFF / 32, DM / 32), tb, 0, stream>>>(W1, W1T, DM, DFF);
    transW<<<dim3(DM / 32, DFF / 32), tb, 0, stream>>>(W2, W2T, DFF, DM);

    // norm_x (gated by iter)
    ln_bf16<<<MROWS, 256, 0, stream>>>(x, lag, lab, NXb, iter);

    // projections: flat bf16 [8192][1024];  Q scaled by 1/sqrt(64) after bias
    gemm_bf16<128, 128, 2, 0><<<dim3(DM / 128, MROWS / 128, 1), 256, 0, stream>>>(
        NXb, 0, 0, DM, WqT, 0, 0, DM, Qb, 0, 0, DM, bq, 0.125f, DM);
    gemm_bf16<128, 128, 2, 0><<<dim3(DM / 128, MROWS / 128, 1), 256, 0, stream>>>(
        NXb, 0, 0, DM, WkT, 0, 0, DM, Kb, 0, 0, DM, bk, 1.0f, DM);
    gemm_bf16<128, 128, 2, 0><<<dim3(DM / 128, MROWS / 128, 1), 256, 0, stream>>>(
        NXb, 0, 0, DM, WvT, 0, 0, DM, Vb, 0, 0, DM, bv, 1.0f, DM);

    transV<<<dim3(SEQ / 32, DH / 32, B_N * NH), tb, 0, stream>>>(Vb, Vt);

    // attention in 4 chunks of 32 heads (= 2 batches each)
    for (int c = 0; c < 4; ++c) {
        const u16* Qc = Qb + (size_t)c * 2 * 1048576;
        const u16* Kc = Kb + (size_t)c * 2 * 1048576;
        // scores[z][q][k] = Q . K   (z local head; base = (z/16)*1M + (z%16)*64)
        gemm_bf16<128, 128, 2, 0><<<dim3(8, 8, 32), 256, 0, stream>>>(
            Qc, 1048576, 64, DM, Kc, 1048576, 64, DM,
            scores, 16777216, 1048576, SEQ, nullptr, 1.0f, DH);
        softmax_mask<<<dim3(SEQ, 32), 256, 0, stream>>>(scores);
        // ctx[z][q][d] = attn . V^T
        gemm_bf16<256, 64, 1, 0><<<dim3(1, 4, 32), 256, 0, stream>>>(
            scores, 16777216, 1048576, SEQ,
            Vt + (size_t)c * 2097152, 1048576, 65536, SEQ,
            (void*)(ctx + (size_t)c * 2097152), 1048576, 65536, DH,
            nullptr, 1.0f, SEQ);
    }

    // out = x + context (reshape bug free via flat add)
    resid_add<<<(MROWS * DM) / 1024, 256, 0, stream>>>(ctx, x, out);

    // FFN: h1 = LN(out); h2 = gelu(h1@W1+b1); out += h2@W2+b2
    ln_bf16<<<MROWS, 256, 0, stream>>>(out, lfg, lfb, h1, nullptr);
    gemm_bf16<128, 128, 2, 1><<<dim3(DFF / 128, MROWS / 128, 1), 256, 0, stream>>>(
        h1, 0, 0, DM, W1T, 0, 0, DM, h2, 0, 0, DFF, b1, 1.0f, DM);
    gemm_bf16<128, 128, 2, 2><<<dim3(DM / 128, MROWS / 128, 1), 256, 0, stream>>>(
        h2, 0, 0, DFF, W2T, 0, 0, DFF, (void*)out, 0, 0, DM, b2, 1.0f, DFF);
}

// Round 2
// 776.757 us; speedup vs baseline: 1.0151x; 1.0151x over previous
//
#include <hip/hip_runtime.h>

// ---------------------------------------------------------------------------
// EncoderLayer: pre-LN attn (gated by iter!=0) + causal-mult-mask attention +
// residual + pre-LN FFN(GELU) + residual.  B=8 S=1024 D=1024 FF=4096 H=16 Dh=64
// R2: big GEMMs moved to 8-phase 256^2 / 128x256 template (T2 swizzle + T3
// phase interleave + T5 setprio, per-K-tile vmcnt drain). Attention still on
// the R1 128^2 kernel (flash fusion is the next step).
// ---------------------------------------------------------------------------

#define B_N 8
#define SEQ 1024
#define DM 1024
#define DFF 4096
#define NH 16
#define DH 64
#define MROWS (B_N * SEQ) // 8192

typedef __attribute__((ext_vector_type(4))) float f32x4;
typedef __attribute__((ext_vector_type(8))) short short8;
typedef __attribute__((ext_vector_type(4))) unsigned short us4;
typedef unsigned short u16;

__device__ __forceinline__ float b2f(u16 u) { return __uint_as_float(((unsigned)u) << 16); }
__device__ __forceinline__ u16 f2b(float f) {
    unsigned u = __float_as_uint(f);
    return (u16)((u + 0x7fffu + ((u >> 16) & 1u)) >> 16); // RNE
}
__device__ __forceinline__ float gelu_f(float x) {
    float t = tanhf(0.7978845608028654f * (x + 0.044715f * x * x * x));
    return 0.5f * x * (1.0f + t);
}
__device__ __forceinline__ void async_cp16(const void* g, void* l) {
    __builtin_amdgcn_global_load_lds(
        (const __attribute__((address_space(1))) unsigned int*)g,
        (__attribute__((address_space(3))) unsigned int*)l, 16, 0, 0);
}

// ---------------------------------------------------------------------------
// 8-phase GEMM:  C[m][n] = (sum_k A[m][k]*Bt[n][k] + bias[n]) * scale
// 512 thr = 8 waves (2M x 4N).  BK=64, double-buffered LDS, st_16x32 swizzle.
// BM=256: wave tile 128x64 (MF=8, MG=2, 16 MFMA/phase)
// BM=128: wave tile  64x64 (MF=4, MG=1,  8 MFMA/phase)
// EPI: 0 = bf16 out; 1 = bf16 GELU out; 2 = fp32 C += v
// ---------------------------------------------------------------------------
#define G8_MFMA(p)                                                              \
    _Pragma("unroll") for (int ks = 0; ks < 2; ++ks)                            \
    _Pragma("unroll") for (int m2 = 0; m2 < MG; ++m2)                           \
    _Pragma("unroll") for (int ni = 0; ni < 4; ++ni)                            \
        acc[(p) * MG + m2][ni] = __builtin_amdgcn_mfma_f32_16x16x32_bf16(       \
            af[m2][ks], bf[ni][ks], acc[(p) * MG + m2][ni], 0, 0, 0)

#define G8_RDA(p)                                                               \
    _Pragma("unroll") for (int m2 = 0; m2 < MG; ++m2)                           \
    _Pragma("unroll") for (int ks = 0; ks < 2; ++ks)                            \
        af[m2][ks] = *(const short8*)(ARd + ((p) * MG + m2) * 2048 + ks * 64)

#define G8_SYNC()                                                               \
    __builtin_amdgcn_s_barrier();                                               \
    asm volatile("s_waitcnt lgkmcnt(0)" ::: "memory");                          \
    __builtin_amdgcn_s_setprio(1)

#define G8_END()                                                                \
    __builtin_amdgcn_s_setprio(0);                                              \
    __builtin_amdgcn_s_barrier()

#define G8_TILE(c, t, doStage)                                                  \
    {                                                                           \
        const char* ARd = lds + (c) * BUFB + wm * AHALF + laneoff;              \
        const char* BRd = lds + (c) * BUFB + 2 * AHALF + (wn >> 1) * BHALF      \
                          + (wn & 1) * 8192 + laneoff;                          \
        short8 bf[4][2], af[MG][2];                                             \
        /* phase 1: read all B-frags + A group 0, stage next A-half0 */         \
        _Pragma("unroll") for (int ni = 0; ni < 4; ++ni)                        \
        _Pragma("unroll") for (int ks = 0; ks < 2; ++ks)                        \
            bf[ni][ks] = *(const short8*)(BRd + ni * 2048 + ks * 64);           \
        G8_RDA(0);                                                              \
        if (doStage) stageA(1 - (c), 0, (t) + 1);                               \
        G8_SYNC(); G8_MFMA(0); G8_END();                                        \
        /* phase 2 */                                                           \
        G8_RDA(1);                                                              \
        if (doStage) stageA(1 - (c), 1, (t) + 1);                               \
        G8_SYNC(); G8_MFMA(1); G8_END();                                        \
        /* phase 3 */                                                           \
        G8_RDA(2);                                                              \
        if (doStage) stageB(1 - (c), 0, (t) + 1);                               \
        G8_SYNC(); G8_MFMA(2); G8_END();                                        \
        /* phase 4: drain staged loads before the tile-boundary barrier */      \
        G8_RDA(3);                                                              \
        if (doStage) stageB(1 - (c), 1, (t) + 1);                               \
        G8_SYNC(); G8_MFMA(3);                                                  \
        __builtin_amdgcn_s_setprio(0);                                          \
        if (doStage) asm volatile("s_waitcnt vmcnt(0)" ::: "memory");           \
        __builtin_amdgcn_s_barrier();                                           \
    }

template <int BM, int BN, int EPI>
__global__ __launch_bounds__(512, 2) void gemm8(
    const u16* __restrict__ A, int lda,
    const u16* __restrict__ Bt, int ldb,
    void* __restrict__ C, int ldc,
    const float* __restrict__ bias, float scale, int K)
{
    constexpr int MF = BM / 32;      // M-frags per wave
    constexpr int MG = MF / 4;       // M-frags per phase
    constexpr int LA = BM / 128;     // gload_lds per thread per A-half
    constexpr int LB = BN / 128;
    constexpr int AHALF = BM * 64;   // bytes per A-half  ((BM/2) rows x 128B)
    constexpr int BHALF = BN * 64;
    constexpr int BUFB = 2 * (AHALF + BHALF);
    __shared__ __align__(16) char lds[2 * BUFB];

    const int tid = threadIdx.x;
    const int lane = tid & 63;
    const int w = tid >> 6;
    const int wm = w >> 2, wn = w & 3;
    const int rr = lane & 15, qq = lane >> 4;
    const int m0 = blockIdx.y * BM, n0 = blockIdx.x * BN;
    // st_16x32 read swizzle: byte ^= ((byte>>9)&1)<<5 ; bit9 = row bit2 = rr bit2
    const int laneoff = (rr * 128 + qq * 16) ^ ((rr & 4) << 3);

    f32x4 acc[MF][4];
#pragma unroll
    for (int i = 0; i < MF; i++)
#pragma unroll
        for (int j = 0; j < 4; j++)
#pragma unroll
            for (int e = 0; e < 4; e++) acc[i][j][e] = 0.f;

    // staging: linear LDS dest granule g; source granule is swizzle-permuted
    // (g' = g ^ (((g>>5)&1)<<1)) so that swizzled reads see logical data.
    auto stageA = [&](int nb, int h, int t) {
#pragma unroll
        for (int i = 0; i < LA; ++i) {
            int g = tid + i * 512;
            int gs = g ^ (((g >> 5) & 1) << 1);
            const u16* src = A + (size_t)(m0 + h * (BM / 2) + (gs >> 3)) * lda
                             + (t << 6) + ((gs & 7) << 3);
            async_cp16(src, lds + nb * BUFB + h * AHALF + g * 16);
        }
    };
    auto stageB = [&](int nb, int h, int t) {
#pragma unroll
        for (int i = 0; i < LB; ++i) {
            int g = tid + i * 512;
            int gs = g ^ (((g >> 5) & 1) << 1);
            const u16* src = Bt + (size_t)(n0 + h * (BN / 2) + (gs >> 3)) * ldb
                             + (t << 6) + ((gs & 7) << 3);
            async_cp16(src, lds + nb * BUFB + 2 * AHALF + h * BHALF + g * 16);
        }
    };

    // prologue: stage tile 0 fully, drain, sync
    stageA(0, 0, 0); stageA(0, 1, 0); stageB(0, 0, 0); stageB(0, 1, 0);
    asm volatile("s_waitcnt vmcnt(0)" ::: "memory");
    __builtin_amdgcn_s_barrier();

    const int NT = K >> 6; // K-tiles of 64 (always even here: 16 or 64)
    for (int t = 0; t < NT; t += 2) {
        G8_TILE(0, t, true);
        G8_TILE(1, t + 1, (t + 2) < NT);
    }

    // epilogue: C/D layout col=lane&15, row=(lane>>4)*4+j
    const int ccol = n0 + wn * 64 + rr;
    const int crow = m0 + wm * (BM / 2) + qq * 4;
#pragma unroll
    for (int mi = 0; mi < MF; ++mi) {
#pragma unroll
        for (int ni = 0; ni < 4; ++ni) {
            const int colg = ccol + ni * 16;
            const float bv = bias ? bias[colg] : 0.f;
#pragma unroll
            for (int j = 0; j < 4; ++j) {
                const int rowg = crow + mi * 16 + j;
                float v = (acc[mi][ni][j] + bv) * scale;
                size_t idx = (size_t)rowg * ldc + colg;
                if (EPI == 1) v = gelu_f(v);
                if (EPI == 2) ((float*)C)[idx] += v;
                else ((u16*)C)[idx] = f2b(v);
            }
        }
    }
}

// ---------------------------------------------------------------------------
// R1 128^2 GEMM kept for the attention QK^T / PV steps (small K / batched z).
// ---------------------------------------------------------------------------
template <int TM, int TN, int WC, int EPI>
__global__ __launch_bounds__(256) void gemm_bf16(
    const u16* __restrict__ A, long long sA1, long long sA2, int lda,
    const u16* __restrict__ Bt, long long sB1, long long sB2, int ldb,
    void* __restrict__ C, long long sC1, long long sC2, int ldc,
    const float* __restrict__ bias, float scale, int K)
{
    __shared__ __align__(16) u16 smem[(TM + TN) * 32];
    u16* As = smem;
    u16* Bs = smem + TM * 32;

    const int tid = threadIdx.x;
    const int lane = tid & 63;
    const int w = tid >> 6;
    const int wr = w / WC, wc = w % WC;

    const int z = blockIdx.z;
    const int zq = z >> 4, zr = z & 15;
    const u16* Ab = A + (long long)zq * sA1 + (long long)zr * sA2;
    const u16* Bb = Bt + (long long)zq * sB1 + (long long)zr * sB2;

    const int m0 = blockIdx.y * TM;
    const int n0 = blockIdx.x * TN;

    f32x4 acc[4][4];
#pragma unroll
    for (int i = 0; i < 4; i++)
#pragma unroll
        for (int j = 0; j < 4; j++)
#pragma unroll
            for (int e = 0; e < 4; e++) acc[i][j][e] = 0.f;

    for (int kt = 0; kt < K; kt += 32) {
#pragma unroll
        for (int i = 0; i < TM / 64; i++) {
            int g = tid + i * 256;
            int row = g >> 2;
            int cole = (g & 3) << 3;
            async_cp16(Ab + (size_t)(m0 + row) * lda + kt + cole, (char*)As + g * 16);
        }
#pragma unroll
        for (int i = 0; i < TN / 64; i++) {
            int g = tid + i * 256;
            int row = g >> 2;
            int cole = (g & 3) << 3;
            async_cp16(Bb + (size_t)(n0 + row) * ldb + kt + cole, (char*)Bs + g * 16);
        }
        __syncthreads();

        short8 af[4], bfr[4];
        const int rr = lane & 15;
        const int kb = (lane >> 4) << 3;
#pragma unroll
        for (int mi = 0; mi < 4; mi++)
            af[mi] = *(const short8*)&As[(wr * 64 + mi * 16 + rr) * 32 + kb];
#pragma unroll
        for (int ni = 0; ni < 4; ni++)
            bfr[ni] = *(const short8*)&Bs[(wc * 64 + ni * 16 + rr) * 32 + kb];
#pragma unroll
        for (int mi = 0; mi < 4; mi++)
#pragma unroll
            for (int ni = 0; ni < 4; ni++)
                acc[mi][ni] = __builtin_amdgcn_mfma_f32_16x16x32_bf16(
                    af[mi], bfr[ni], acc[mi][ni], 0, 0, 0);
        __syncthreads();
    }

    const long long cz = (long long)zq * sC1 + (long long)zr * sC2;
    const int r0 = (lane >> 4) << 2;
    const int ccol = lane & 15;
#pragma unroll
    for (int mi = 0; mi < 4; mi++) {
#pragma unroll
        for (int ni = 0; ni < 4; ni++) {
            int colg = n0 + wc * 64 + ni * 16 + ccol;
            float bv = bias ? bias[colg] : 0.f;
#pragma unroll
            for (int j = 0; j < 4; j++) {
                int rowg = m0 + wr * 64 + mi * 16 + r0 + j;
                float v = (acc[mi][ni][j] + bv) * scale;
                long long idx = cz + (long long)rowg * ldc + colg;
                if (EPI == 1) v = gelu_f(v);
                if (EPI == 2) {
                    float* Cf = (float*)C;
                    Cf[idx] += v;
                } else {
                    ((u16*)C)[idx] = f2b(v);
                }
            }
        }
    }
}

// ---------------------------------------------------------------------------
__global__ __launch_bounds__(256) void ln_bf16(
    const float* __restrict__ in, const float* __restrict__ gg,
    const float* __restrict__ bb, u16* __restrict__ outp,
    const int* __restrict__ iterp)
{
    const int row = blockIdx.x;
    const int t = threadIdx.x;
    const int lane = t & 63, w = t >> 6;
    const float* r = in + (size_t)row * DM;
    f32x4 x = *(const f32x4*)(r + t * 4);
    __shared__ float red[4];

    float s = x[0] + x[1] + x[2] + x[3];
#pragma unroll
    for (int o = 32; o; o >>= 1) s += __shfl_xor(s, o, 64);
    if (lane == 0) red[w] = s;
    __syncthreads();
    float mu = (red[0] + red[1] + red[2] + red[3]) * (1.0f / DM);
    __syncthreads();

    float d0 = x[0] - mu, d1 = x[1] - mu, d2 = x[2] - mu, d3 = x[3] - mu;
    float q = d0 * d0 + d1 * d1 + d2 * d2 + d3 * d3;
#pragma unroll
    for (int o = 32; o; o >>= 1) q += __shfl_xor(q, o, 64);
    if (lane == 0) red[w] = q;
    __syncthreads();
    float rs = rsqrtf((red[0] + red[1] + red[2] + red[3]) * (1.0f / DM) + 1e-6f);

    bool apply = !(iterp && iterp[0] == 0);
    f32x4 gv = *(const f32x4*)(gg + t * 4);
    f32x4 bv = *(const f32x4*)(bb + t * 4);
    us4 o;
    if (apply) {
        o[0] = f2b(d0 * rs * gv[0] + bv[0]);
        o[1] = f2b(d1 * rs * gv[1] + bv[1]);
        o[2] = f2b(d2 * rs * gv[2] + bv[2]);
        o[3] = f2b(d3 * rs * gv[3] + bv[3]);
    } else {
        o[0] = f2b(x[0]); o[1] = f2b(x[1]); o[2] = f2b(x[2]); o[3] = f2b(x[3]);
    }
    *(us4*)(outp + (size_t)row * DM + t * 4) = o;
}

// ---------------------------------------------------------------------------
__global__ __launch_bounds__(256) void softmax_mask(u16* __restrict__ sc)
{
    const int qrow = blockIdx.x;
    u16* rowp = sc + ((size_t)blockIdx.y << 20) + (size_t)qrow * SEQ;
    const int t = threadIdx.x, lane = t & 63, w = t >> 6;
    __shared__ float red[4];

    us4 r4 = *(const us4*)(rowp + t * 4);
    float v[4];
#pragma unroll
    for (int j = 0; j < 4; j++) {
        int k = t * 4 + j;
        v[j] = (k <= qrow) ? b2f(r4[j]) : 0.f;
    }
    float m = fmaxf(fmaxf(v[0], v[1]), fmaxf(v[2], v[3]));
#pragma unroll
    for (int o = 32; o; o >>= 1) m = fmaxf(m, __shfl_xor(m, o, 64));
    if (lane == 0) red[w] = m;
    __syncthreads();
    m = fmaxf(fmaxf(red[0], red[1]), fmaxf(red[2], red[3]));
    __syncthreads();
    float e0 = expf(v[0] - m), e1 = expf(v[1] - m), e2 = expf(v[2] - m), e3 = expf(v[3] - m);
    float s = e0 + e1 + e2 + e3;
#pragma unroll
    for (int o = 32; o; o >>= 1) s += __shfl_xor(s, o, 64);
    if (lane == 0) red[w] = s;
    __syncthreads();
    float inv = 1.0f / (red[0] + red[1] + red[2] + red[3]);
    us4 o;
    o[0] = f2b(e0 * inv); o[1] = f2b(e1 * inv); o[2] = f2b(e2 * inv); o[3] = f2b(e3 * inv);
    *(us4*)(rowp + t * 4) = o;
}

__global__ void transW(const float* __restrict__ W, u16* __restrict__ WT, int Kd, int Nd)
{
    __shared__ float tile[32][33];
    int bx = blockIdx.x << 5, by = blockIdx.y << 5;
    int tx = threadIdx.x, ty = threadIdx.y;
#pragma unroll
    for (int i = 0; i < 32; i += 8)
        tile[ty + i][tx] = W[(size_t)(by + ty + i) * Nd + bx + tx];
    __syncthreads();
#pragma unroll
    for (int i = 0; i < 32; i += 8)
        WT[(size_t)(bx + ty + i) * Kd + by + tx] = f2b(tile[tx][ty + i]);
}

__global__ void transV(const u16* __restrict__ Vb, u16* __restrict__ Vt)
{
    __shared__ u16 tile[32][33];
    int s0 = blockIdx.x << 5, d0 = blockIdx.y << 5, bh = blockIdx.z;
    int b = bh >> 4, h = bh & 15;
    int tx = threadIdx.x, ty = threadIdx.y;
#pragma unroll
    for (int i = 0; i < 32; i += 8)
        tile[ty + i][tx] = Vb[(size_t)((b << 10) + s0 + ty + i) * DM + (h << 6) + d0 + tx];
    __syncthreads();
#pragma unroll
    for (int i = 0; i < 32; i += 8)
        Vt[((size_t)bh << 16) + (size_t)(d0 + ty + i) * SEQ + s0 + tx] = tile[tx][ty + i];
}

__global__ __launch_bounds__(256) void resid_add(
    const u16* __restrict__ ctx, const float* __restrict__ x, float* __restrict__ outp)
{
    size_t i = ((size_t)blockIdx.x * 256 + threadIdx.x) * 4;
    us4 c = *(const us4*)(ctx + i);
    f32x4 xv = *(const f32x4*)(x + i);
    f32x4 o;
#pragma unroll
    for (int j = 0; j < 4; j++) o[j] = xv[j] + b2f(c[j]);
    *(f32x4*)(outp + i) = o;
}

// ---------------------------------------------------------------------------
extern "C" void kernel_launch(void* const* d_in, const int* in_sizes, int n_in,
                              void* d_out, int out_size, void* d_ws, size_t ws_size,
                              hipStream_t stream)
{
    const int* iter = (const int*)d_in[0];
    const float* x = (const float*)d_in[1];
    const float* Wq = (const float*)d_in[3];
    const float* bq = (const float*)d_in[4];
    const float* Wk = (const float*)d_in[5];
    const float* bk = (const float*)d_in[6];
    const float* Wv = (const float*)d_in[7];
    const float* bv = (const float*)d_in[8];
    const float* W1 = (const float*)d_in[9];
    const float* b1 = (const float*)d_in[10];
    const float* W2 = (const float*)d_in[11];
    const float* b2 = (const float*)d_in[12];
    const float* lag = (const float*)d_in[13];
    const float* lab = (const float*)d_in[14];
    const float* lfg = (const float*)d_in[15];
    const float* lfb = (const float*)d_in[16];
    float* out = (float*)d_out;

    char* ws = (char*)d_ws;
    size_t off = 0;
    auto alloc = [&](size_t bytes) {
        char* p = ws + off;
        off += (bytes + 255) & ~(size_t)255;
        return p;
    };
    u16* NXb = (u16*)alloc((size_t)MROWS * DM * 2);
    u16* Qb  = (u16*)alloc((size_t)MROWS * DM * 2);
    u16* Kb  = (u16*)alloc((size_t)MROWS * DM * 2);
    u16* Vb  = (u16*)alloc((size_t)MROWS * DM * 2);
    u16* ctx = (u16*)alloc((size_t)MROWS * DM * 2);
    u16* h2  = (u16*)alloc((size_t)MROWS * DFF * 2);
    u16* WqT = (u16*)alloc((size_t)DM * DM * 2);
    u16* WkT = (u16*)alloc((size_t)DM * DM * 2);
    u16* WvT = (u16*)alloc((size_t)DM * DM * 2);
    u16* W1T = (u16*)alloc((size_t)DM * DFF * 2);
    u16* W2T = (u16*)alloc((size_t)DM * DFF * 2);
    u16* Vt = NXb;
    u16* h1 = Qb;
    u16* scores = h2;

    dim3 tb(32, 8);
    transW<<<dim3(DM / 32, DM / 32), tb, 0, stream>>>(Wq, WqT, DM, DM);
    transW<<<dim3(DM / 32, DM / 32), tb, 0, stream>>>(Wk, WkT, DM, DM);
    transW<<<dim3(DM / 32, DM / 32), tb, 0, stream>>>(Wv, WvT, DM, DM);
    transW<<<dim3(DFF / 32, DM / 32), tb, 0, stream>>>(W1, W1T, DM, DFF);
    transW<<<dim3(DM / 32, DFF / 32), tb, 0, stream>>>(W2, W2T, DFF, DM);

    ln_bf16<<<MROWS, 256, 0, stream>>>(x, lag, lab, NXb, iter);

    // projections (8-phase 128x256, 256 blocks each): Q scaled by 1/sqrt(64)
    gemm8<128, 256, 0><<<dim3(DM / 256, MROWS / 128), 512, 0, stream>>>(
        NXb, DM, WqT, DM, Qb, DM, bq, 0.125f, DM);
    gemm8<128, 256, 0><<<dim3(DM / 256, MROWS / 128), 512, 0, stream>>>(
        NXb, DM, WkT, DM, Kb, DM, bk, 1.0f, DM);
    gemm8<128, 256, 0><<<dim3(DM / 256, MROWS / 128), 512, 0, stream>>>(
        NXb, DM, WvT, DM, Vb, DM, bv, 1.0f, DM);

    transV<<<dim3(SEQ / 32, DH / 32, B_N * NH), tb, 0, stream>>>(Vb, Vt);

    // attention in 4 chunks of 32 heads (R1 kernels)
    for (int c = 0; c < 4; ++c) {
        const u16* Qc = Qb + (size_t)c * 2 * 1048576;
        const u16* Kc = Kb + (size_t)c * 2 * 1048576;
        gemm_bf16<128, 128, 2, 0><<<dim3(8, 8, 32), 256, 0, stream>>>(
            Qc, 1048576, 64, DM, Kc, 1048576, 64, DM,
            scores, 16777216, 1048576, SEQ, nullptr, 1.0f, DH);
        softmax_mask<<<dim3(SEQ, 32), 256, 0, stream>>>(scores);
        gemm_bf16<256, 64, 1, 0><<<dim3(1, 4, 32), 256, 0, stream>>>(
            scores, 16777216, 1048576, SEQ,
            Vt + (size_t)c * 2097152, 1048576, 65536, SEQ,
            (void*)(ctx + (size_t)c * 2097152), 1048576, 65536, DH,
            nullptr, 1.0f, SEQ);
    }

    resid_add<<<(MROWS * DM) / 1024, 256, 0, stream>>>(ctx, x, out);

    // FFN: h1 = LN(out); h2 = gelu(h1@W1+b1) [8-phase 256^2];
    //      out += h2@W2+b2 [8-phase 128x256]
    ln_bf16<<<MROWS, 256, 0, stream>>>(out, lfg, lfb, h1, nullptr);
    gemm8<256, 256, 1><<<dim3(DFF / 256, MROWS / 256), 512, 0, stream>>>(
        h1, DM, W1T, DM, h2, DFF, b1, 1.0f, DM);
    gemm8<128, 256, 2><<<dim3(DM / 256, MROWS / 128), 512, 0, stream>>>(
        h2, DFF, W2T, DFF, (void*)out, DM, b2, 1.0f, DFF);
}